// Round 1
// baseline (519.144 us; speedup 1.0000x reference)
//
#include <hip/hip_runtime.h>
#include <hip/hip_bf16.h>

#define N_LANG 2048
#define D_EMB  64
#define V_VOC  2048
#define TILE   16

// ws layout: [0:4) uint max_bits ; [4:8) uint mask_count ; [8:16) double sum

__global__ void max_kernel(const float4* __restrict__ m, unsigned* __restrict__ wmax, int n4) {
    float v = 0.0f;  // map_dist values are >= 0
    for (int i = blockIdx.x * blockDim.x + threadIdx.x; i < n4; i += gridDim.x * blockDim.x) {
        float4 x = m[i];
        v = fmaxf(v, fmaxf(fmaxf(x.x, x.y), fmaxf(x.z, x.w)));
    }
    #pragma unroll
    for (int o = 32; o > 0; o >>= 1)
        v = fmaxf(v, __shfl_down(v, o));
    if ((threadIdx.x & 63) == 0)
        atomicMax(wmax, __float_as_uint(v));  // bit order == float order for v >= 0
}

__global__ __launch_bounds__(256) void loss_kernel(
    const int* __restrict__ ids, const float* __restrict__ emb,
    const float* __restrict__ tree, const float* __restrict__ mapd,
    const unsigned* __restrict__ wmax_bits,
    double* __restrict__ wsum, unsigned* __restrict__ wcnt)
{
    __shared__ __align__(16) float Ei[TILE][68];  // +4 pad: bank stride 68%32=4 -> 2-way max (free)
    __shared__ __align__(16) float Ej[TILE][68];
    __shared__ int idi[TILE];
    __shared__ int idj[TILE];

    const int bi = blockIdx.x, bj = blockIdx.y;
    const int tid = threadIdx.x;

    // Stage embedding tiles: 16 rows x 64 floats each side; 256 threads, 1 float4 each per side.
    {
        int r = tid >> 4;           // 0..15
        int c = (tid & 15) << 2;    // 0,4,...,60
        const float4 a = *(const float4*)(emb + (size_t)(bi * TILE + r) * D_EMB + c);
        const float4 b = *(const float4*)(emb + (size_t)(bj * TILE + r) * D_EMB + c);
        *(float4*)&Ei[r][c] = a;
        *(float4*)&Ej[r][c] = b;
    }
    if (tid < TILE)              idi[tid] = ids[bi * TILE + tid];
    else if (tid < 2 * TILE)     idj[tid - TILE] = ids[bj * TILE + (tid - TILE)];
    __syncthreads();

    const int ti = tid >> 4;    // i within tile
    const int tj = tid & 15;    // j within tile

    float acc = 0.0f;
    #pragma unroll
    for (int d = 0; d < D_EMB; d += 4) {
        float4 a = *(const float4*)&Ei[ti][d];
        float4 b = *(const float4*)&Ej[tj][d];
        acc += fabsf(a.x - b.x) + fabsf(a.y - b.y) + fabsf(a.z - b.z) + fabsf(a.w - b.w);
    }
    const float emb_dist = acc * (1.0f / (float)D_EMB);

    const int ia = idi[ti];
    const int ja = idj[tj];
    float pp = 0.0f;
    unsigned msk = 0u;
    if (ia != ja) {
        const float largest = __uint_as_float(wmax_bits[0]);
        const size_t off = (size_t)ia * V_VOC + (size_t)ja;
        const float t  = tree[off];
        const float mp = mapd[off];
        const float metric = (t + mp / largest) * 0.5f;
        pp = fabsf(emb_dist - metric);
        msk = 1u;
    }

    // Reduce across the block: wave shuffle then LDS across 4 waves.
    #pragma unroll
    for (int o = 32; o > 0; o >>= 1) {
        pp  += __shfl_down(pp, o);
        msk += __shfl_down(msk, o);
    }
    __shared__ float   wsum_l[4];
    __shared__ unsigned wcnt_l[4];
    const int wave = tid >> 6;
    if ((tid & 63) == 0) { wsum_l[wave] = pp; wcnt_l[wave] = msk; }
    __syncthreads();
    if (tid == 0) {
        float   s = wsum_l[0] + wsum_l[1] + wsum_l[2] + wsum_l[3];
        unsigned c = wcnt_l[0] + wcnt_l[1] + wcnt_l[2] + wcnt_l[3];
        atomicAdd(wsum, (double)s);
        atomicAdd(wcnt, c);
    }
}

__global__ void finalize_kernel(const double* __restrict__ wsum,
                                const unsigned* __restrict__ wcnt,
                                float* __restrict__ out)
{
    if (threadIdx.x == 0 && blockIdx.x == 0)
        out[0] = (float)(wsum[0] / (double)wcnt[0]);
}

extern "C" void kernel_launch(void* const* d_in, const int* in_sizes, int n_in,
                              void* d_out, int out_size, void* d_ws, size_t ws_size,
                              hipStream_t stream) {
    const int*   ids  = (const int*)d_in[0];
    const float* emb  = (const float*)d_in[1];
    const float* tree = (const float*)d_in[2];
    const float* mapd = (const float*)d_in[3];
    float* out = (float*)d_out;

    unsigned* wmax = (unsigned*)d_ws;                       // [0:4)
    unsigned* wcnt = (unsigned*)((char*)d_ws + 4);          // [4:8)
    double*   wsum = (double*)((char*)d_ws + 8);            // [8:16)

    hipMemsetAsync(d_ws, 0, 16, stream);

    max_kernel<<<1024, 256, 0, stream>>>((const float4*)mapd, wmax, (V_VOC * V_VOC) / 4);

    dim3 grid(N_LANG / TILE, N_LANG / TILE);
    loss_kernel<<<grid, 256, 0, stream>>>(ids, emb, tree, mapd, wmax, wsum, wcnt);

    finalize_kernel<<<1, 64, 0, stream>>>(wsum, wcnt, out);
}

// Round 2
// 438.342 us; speedup vs baseline: 1.1843x; 1.1843x over previous
//
#include <hip/hip_runtime.h>
#include <hip/hip_bf16.h>

#define NL 2048   // languages
#define DE 64     // embedding dim
#define VV 2048   // vocab
#define BT 64     // block pair-tile (64x64 pairs per block)
#define ST 68     // LDS row stride in floats (68%32==4 -> <=2-way aliasing on reads)

// ws layout: [0:4) uint max_bits ; [4:8) uint mask_count ; [8:16) double sum

__global__ void max_kernel(const float4* __restrict__ m, unsigned* __restrict__ wmax, int n4) {
    float v = 0.0f;  // map_dist values are >= 0
    for (int i = blockIdx.x * blockDim.x + threadIdx.x; i < n4; i += gridDim.x * blockDim.x) {
        float4 x = m[i];
        v = fmaxf(v, fmaxf(fmaxf(x.x, x.y), fmaxf(x.z, x.w)));
    }
    #pragma unroll
    for (int o = 32; o > 0; o >>= 1)
        v = fmaxf(v, __shfl_down(v, o));
    if ((threadIdx.x & 63) == 0)
        atomicMax(wmax, __float_as_uint(v));  // bit order == float order for v >= 0
}

__global__ __launch_bounds__(256, 3) void loss_kernel(
    const int* __restrict__ ids, const float* __restrict__ emb,
    const float* __restrict__ tree, const float* __restrict__ mapd,
    const unsigned* __restrict__ wmax_bits,
    double* __restrict__ wsum, unsigned* __restrict__ wcnt)
{
    __shared__ __align__(16) float Ei[BT][ST];   // [i][dim]
    __shared__ __align__(16) float Ejt[DE][ST];  // [dim][j]  (transposed -> conflict-free f4 reads)
    __shared__ int idi[BT];
    __shared__ int idj[BT];

    const int tid = threadIdx.x;
    const int bi = blockIdx.x, bj = blockIdx.y;

    // ---- Stage tiles: each thread loads 16 floats (4 x float4) per side ----
    {
        const int r  = tid & 63;          // row within tile
        const int c0 = (tid >> 6) << 4;   // dim chunk: 0,16,32,48
        const float4* pa = (const float4*)(emb + (size_t)(bi * BT + r) * DE + c0);
        const float4* pb = (const float4*)(emb + (size_t)(bj * BT + r) * DE + c0);
        float4 a0 = pa[0], a1 = pa[1], a2 = pa[2], a3 = pa[3];
        float4 b0 = pb[0], b1 = pb[1], b2 = pb[2], b3 = pb[3];
        *(float4*)&Ei[r][c0 + 0]  = a0;
        *(float4*)&Ei[r][c0 + 4]  = a1;
        *(float4*)&Ei[r][c0 + 8]  = a2;
        *(float4*)&Ei[r][c0 + 12] = a3;
        // transpose B into Ejt: 16 scalar writes, lanes r=0..63 consecutive -> 2-way max
        Ejt[c0 + 0][r]  = b0.x; Ejt[c0 + 1][r]  = b0.y; Ejt[c0 + 2][r]  = b0.z; Ejt[c0 + 3][r]  = b0.w;
        Ejt[c0 + 4][r]  = b1.x; Ejt[c0 + 5][r]  = b1.y; Ejt[c0 + 6][r]  = b1.z; Ejt[c0 + 7][r]  = b1.w;
        Ejt[c0 + 8][r]  = b2.x; Ejt[c0 + 9][r]  = b2.y; Ejt[c0 + 10][r] = b2.z; Ejt[c0 + 11][r] = b2.w;
        Ejt[c0 + 12][r] = b3.x; Ejt[c0 + 13][r] = b3.y; Ejt[c0 + 14][r] = b3.z; Ejt[c0 + 15][r] = b3.w;
        if (tid < BT)           idi[tid] = ids[bi * BT + tid];
        else if (tid < 2 * BT)  idj[tid - BT] = ids[bj * BT + (tid - BT)];
    }
    __syncthreads();

    const int ty = tid >> 4, tx = tid & 15;
    const int i0 = ty * 4, j0 = tx * 4;

    // ---- Issue the 32 scattered metric gathers EARLY (hide under VALU loop) ----
    int ia[4], ja[4];
    #pragma unroll
    for (int s = 0; s < 4; ++s) { ia[s] = idi[i0 + s]; ja[s] = idj[j0 + s]; }
    float tg[4][4], mg[4][4];
    #pragma unroll
    for (int s = 0; s < 4; ++s)
        #pragma unroll
        for (int c = 0; c < 4; ++c) {
            const int off = ia[s] * VV + ja[c];
            tg[s][c] = tree[off];
            mg[s][c] = mapd[off];
        }

    // ---- 4x4 register-tiled L1-distance accumulation ----
    float acc[4][4];
    #pragma unroll
    for (int s = 0; s < 4; ++s)
        #pragma unroll
        for (int c = 0; c < 4; ++c) acc[s][c] = 0.0f;

    #pragma unroll
    for (int k = 0; k < 16; ++k) {        // dim chunk d = 4k
        float4 av[4], bv[4];
        #pragma unroll
        for (int s = 0; s < 4; ++s) av[s] = *(const float4*)&Ei[i0 + s][4 * k];
        #pragma unroll
        for (int c = 0; c < 4; ++c) bv[c] = *(const float4*)&Ejt[4 * k + c][j0];
        #pragma unroll
        for (int s = 0; s < 4; ++s) {
            acc[s][0] += fabsf(av[s].x - bv[0].x) + fabsf(av[s].y - bv[1].x)
                       + fabsf(av[s].z - bv[2].x) + fabsf(av[s].w - bv[3].x);
            acc[s][1] += fabsf(av[s].x - bv[0].y) + fabsf(av[s].y - bv[1].y)
                       + fabsf(av[s].z - bv[2].y) + fabsf(av[s].w - bv[3].y);
            acc[s][2] += fabsf(av[s].x - bv[0].z) + fabsf(av[s].y - bv[1].z)
                       + fabsf(av[s].z - bv[2].z) + fabsf(av[s].w - bv[3].z);
            acc[s][3] += fabsf(av[s].x - bv[0].w) + fabsf(av[s].y - bv[1].w)
                       + fabsf(av[s].z - bv[2].w) + fabsf(av[s].w - bv[3].w);
        }
    }

    // ---- Epilogue: metric + masked |diff| ----
    const float largest = __uint_as_float(wmax_bits[0]);
    const float inv = 1.0f / largest;
    float pp = 0.0f;
    unsigned cnt = 0;
    #pragma unroll
    for (int s = 0; s < 4; ++s)
        #pragma unroll
        for (int c = 0; c < 4; ++c) {
            if (ia[s] != ja[c]) {
                const float metric = (tg[s][c] + mg[s][c] * inv) * 0.5f;
                const float ed = acc[s][c] * (1.0f / (float)DE);
                pp += fabsf(ed - metric);
                cnt += 1u;
            }
        }

    // ---- Block reduction ----
    #pragma unroll
    for (int o = 32; o > 0; o >>= 1) {
        pp  += __shfl_down(pp, o);
        cnt += __shfl_down(cnt, o);
    }
    __shared__ float    wsum_l[4];
    __shared__ unsigned wcnt_l[4];
    const int wave = tid >> 6;
    if ((tid & 63) == 0) { wsum_l[wave] = pp; wcnt_l[wave] = cnt; }
    __syncthreads();
    if (tid == 0) {
        float    s = wsum_l[0] + wsum_l[1] + wsum_l[2] + wsum_l[3];
        unsigned c = wcnt_l[0] + wcnt_l[1] + wcnt_l[2] + wcnt_l[3];
        atomicAdd(wsum, (double)s);
        atomicAdd(wcnt, c);
    }
}

__global__ void finalize_kernel(const double* __restrict__ wsum,
                                const unsigned* __restrict__ wcnt,
                                float* __restrict__ out)
{
    if (threadIdx.x == 0 && blockIdx.x == 0)
        out[0] = (float)(wsum[0] / (double)wcnt[0]);
}

extern "C" void kernel_launch(void* const* d_in, const int* in_sizes, int n_in,
                              void* d_out, int out_size, void* d_ws, size_t ws_size,
                              hipStream_t stream) {
    const int*   ids  = (const int*)d_in[0];
    const float* emb  = (const float*)d_in[1];
    const float* tree = (const float*)d_in[2];
    const float* mapd = (const float*)d_in[3];
    float* out = (float*)d_out;

    unsigned* wmax = (unsigned*)d_ws;                       // [0:4)
    unsigned* wcnt = (unsigned*)((char*)d_ws + 4);          // [4:8)
    double*   wsum = (double*)((char*)d_ws + 8);            // [8:16)

    hipMemsetAsync(d_ws, 0, 16, stream);

    max_kernel<<<1024, 256, 0, stream>>>((const float4*)mapd, wmax, (VV * VV) / 4);

    dim3 grid(NL / BT, NL / BT);
    loss_kernel<<<grid, 256, 0, stream>>>(ids, emb, tree, mapd, wmax, wsum, wcnt);

    finalize_kernel<<<1, 64, 0, stream>>>(wsum, wcnt, out);
}

// Round 3
// 213.347 us; speedup vs baseline: 2.4333x; 2.0546x over previous
//
#include <hip/hip_runtime.h>
#include <hip/hip_bf16.h>

#define NL 2048   // languages
#define DE 64     // embedding dim
#define VV 2048   // vocab
#define BT 64     // block pair-tile (64x64 pairs per block)
#define ST 68     // LDS row stride in floats (68%32==4 -> <=2-way aliasing, free)

// ws layout:
// [0:4)          uint max_bits
// [4:8)          uint mask_count
// [8:16)         double sum
// [16:8208)      uint hist[2048]
// [8208:16400)   uint offs[2048]
// [16400:24592)  int  perm[2048]

__global__ void max_kernel(const float4* __restrict__ m, unsigned* __restrict__ wmax, int n4) {
    float v = 0.0f;  // map_dist values are >= 0
    for (int i = blockIdx.x * blockDim.x + threadIdx.x; i < n4; i += gridDim.x * blockDim.x) {
        float4 x = m[i];
        v = fmaxf(v, fmaxf(fmaxf(x.x, x.y), fmaxf(x.z, x.w)));
    }
    #pragma unroll
    for (int o = 32; o > 0; o >>= 1)
        v = fmaxf(v, __shfl_down(v, o));
    if ((threadIdx.x & 63) == 0)
        atomicMax(wmax, __float_as_uint(v));  // bit order == float order for v >= 0
}

__global__ void hist_kernel(const int* __restrict__ ids, unsigned* __restrict__ hist) {
    const int i = blockIdx.x * blockDim.x + threadIdx.x;
    if (i < NL) atomicAdd(&hist[ids[i]], 1u);
}

__global__ __launch_bounds__(256) void scan_kernel(const unsigned* __restrict__ hist,
                                                   unsigned* __restrict__ offs) {
    __shared__ unsigned part[256];
    const int t = threadIdx.x;
    unsigned loc[8];
    unsigned s = 0;
    #pragma unroll
    for (int k = 0; k < 8; ++k) { loc[k] = hist[t * 8 + k]; s += loc[k]; }
    part[t] = s;
    __syncthreads();
    // inclusive scan over 256 partials (read-all, sync, write-all)
    for (int off = 1; off < 256; off <<= 1) {
        unsigned v = (t >= off) ? part[t - off] : 0u;
        __syncthreads();
        part[t] += v;
        __syncthreads();
    }
    unsigned ex = part[t] - s;  // exclusive prefix of this thread's chunk
    #pragma unroll
    for (int k = 0; k < 8; ++k) { offs[t * 8 + k] = ex; ex += loc[k]; }
}

__global__ void scatter_kernel(const int* __restrict__ ids, unsigned* __restrict__ offs,
                               int* __restrict__ perm) {
    const int i = blockIdx.x * blockDim.x + threadIdx.x;
    if (i < NL) {
        const unsigned p = atomicAdd(&offs[ids[i]], 1u);
        perm[p] = i;
    }
}

__global__ __launch_bounds__(256) void loss_kernel(
    const int* __restrict__ ids, const float* __restrict__ emb,
    const float* __restrict__ tree, const float* __restrict__ mapd,
    const int* __restrict__ perm, const unsigned* __restrict__ wmax_bits,
    double* __restrict__ wsum, unsigned* __restrict__ wcnt)
{
    __shared__ __align__(16) float Ei[BT][ST];   // [i][dim]
    __shared__ __align__(16) float Ejt[DE][ST];  // [dim][j]  (transposed)
    __shared__ int idi[BT];
    __shared__ int idj[BT];

    const int tid = threadIdx.x;
    const int bi = blockIdx.x, bj = blockIdx.y;

    // ---- Stage tiles through perm (emb is 512 KB -> L2-resident; rows fully used) ----
    {
        const int r  = tid & 63;          // row within tile
        const int c0 = (tid >> 6) << 4;   // dim chunk: 0,16,32,48
        const int gi = perm[bi * BT + r];
        const int gj = perm[bj * BT + r];
        const float4* pa = (const float4*)(emb + (size_t)gi * DE + c0);
        const float4* pb = (const float4*)(emb + (size_t)gj * DE + c0);
        float4 a0 = pa[0], a1 = pa[1], a2 = pa[2], a3 = pa[3];
        float4 b0 = pb[0], b1 = pb[1], b2 = pb[2], b3 = pb[3];
        *(float4*)&Ei[r][c0 + 0]  = a0;
        *(float4*)&Ei[r][c0 + 4]  = a1;
        *(float4*)&Ei[r][c0 + 8]  = a2;
        *(float4*)&Ei[r][c0 + 12] = a3;
        Ejt[c0 + 0][r]  = b0.x; Ejt[c0 + 1][r]  = b0.y; Ejt[c0 + 2][r]  = b0.z; Ejt[c0 + 3][r]  = b0.w;
        Ejt[c0 + 4][r]  = b1.x; Ejt[c0 + 5][r]  = b1.y; Ejt[c0 + 6][r]  = b1.z; Ejt[c0 + 7][r]  = b1.w;
        Ejt[c0 + 8][r]  = b2.x; Ejt[c0 + 9][r]  = b2.y; Ejt[c0 + 10][r] = b2.z; Ejt[c0 + 11][r] = b2.w;
        Ejt[c0 + 12][r] = b3.x; Ejt[c0 + 13][r] = b3.y; Ejt[c0 + 14][r] = b3.z; Ejt[c0 + 15][r] = b3.w;
        if (tid < BT)           idi[tid] = ids[perm[bi * BT + tid]];
        else if (tid < 2 * BT)  idj[tid - BT] = ids[perm[bj * BT + (tid - BT)]];
    }
    __syncthreads();

    const int ty = tid >> 4, tx = tid & 15;
    const int i0 = ty * 4, j0 = tx * 4;

    // ---- Gather metric early; combine immediately -> only 16 long-lived regs ----
    int ia[4], ja[4];
    #pragma unroll
    for (int s = 0; s < 4; ++s) { ia[s] = idi[i0 + s]; ja[s] = idj[j0 + s]; }
    const float inv = 1.0f / __uint_as_float(wmax_bits[0]);
    float met[4][4];
    #pragma unroll
    for (int s = 0; s < 4; ++s)
        #pragma unroll
        for (int c = 0; c < 4; ++c) {
            const int off = ia[s] * VV + ja[c];   // sorted ids -> tight line locality
            met[s][c] = (tree[off] + mapd[off] * inv) * 0.5f;
        }

    // ---- 4x4 register-tiled L1-distance accumulation ----
    float acc[4][4];
    #pragma unroll
    for (int s = 0; s < 4; ++s)
        #pragma unroll
        for (int c = 0; c < 4; ++c) acc[s][c] = 0.0f;

    #pragma unroll
    for (int k = 0; k < 16; ++k) {        // dim chunk d = 4k
        float4 av[4], bv[4];
        #pragma unroll
        for (int s = 0; s < 4; ++s) av[s] = *(const float4*)&Ei[i0 + s][4 * k];
        #pragma unroll
        for (int c = 0; c < 4; ++c) bv[c] = *(const float4*)&Ejt[4 * k + c][j0];
        #pragma unroll
        for (int s = 0; s < 4; ++s) {
            acc[s][0] += fabsf(av[s].x - bv[0].x) + fabsf(av[s].y - bv[1].x)
                       + fabsf(av[s].z - bv[2].x) + fabsf(av[s].w - bv[3].x);
            acc[s][1] += fabsf(av[s].x - bv[0].y) + fabsf(av[s].y - bv[1].y)
                       + fabsf(av[s].z - bv[2].y) + fabsf(av[s].w - bv[3].y);
            acc[s][2] += fabsf(av[s].x - bv[0].z) + fabsf(av[s].y - bv[1].z)
                       + fabsf(av[s].z - bv[2].z) + fabsf(av[s].w - bv[3].z);
            acc[s][3] += fabsf(av[s].x - bv[0].w) + fabsf(av[s].y - bv[1].w)
                       + fabsf(av[s].z - bv[2].w) + fabsf(av[s].w - bv[3].w);
        }
    }

    // ---- Epilogue: masked |diff| ----
    float pp = 0.0f;
    unsigned cnt = 0;
    #pragma unroll
    for (int s = 0; s < 4; ++s)
        #pragma unroll
        for (int c = 0; c < 4; ++c) {
            if (ia[s] != ja[c]) {
                pp += fabsf(acc[s][c] * (1.0f / (float)DE) - met[s][c]);
                cnt += 1u;
            }
        }

    // ---- Block reduction ----
    #pragma unroll
    for (int o = 32; o > 0; o >>= 1) {
        pp  += __shfl_down(pp, o);
        cnt += __shfl_down(cnt, o);
    }
    __shared__ float    wsum_l[4];
    __shared__ unsigned wcnt_l[4];
    const int wave = tid >> 6;
    if ((tid & 63) == 0) { wsum_l[wave] = pp; wcnt_l[wave] = cnt; }
    __syncthreads();
    if (tid == 0) {
        float    s = wsum_l[0] + wsum_l[1] + wsum_l[2] + wsum_l[3];
        unsigned c = wcnt_l[0] + wcnt_l[1] + wcnt_l[2] + wcnt_l[3];
        atomicAdd(wsum, (double)s);
        atomicAdd(wcnt, c);
    }
}

__global__ void finalize_kernel(const double* __restrict__ wsum,
                                const unsigned* __restrict__ wcnt,
                                float* __restrict__ out)
{
    if (threadIdx.x == 0 && blockIdx.x == 0)
        out[0] = (float)(wsum[0] / (double)wcnt[0]);
}

extern "C" void kernel_launch(void* const* d_in, const int* in_sizes, int n_in,
                              void* d_out, int out_size, void* d_ws, size_t ws_size,
                              hipStream_t stream) {
    const int*   ids  = (const int*)d_in[0];
    const float* emb  = (const float*)d_in[1];
    const float* tree = (const float*)d_in[2];
    const float* mapd = (const float*)d_in[3];
    float* out = (float*)d_out;

    unsigned* wmax = (unsigned*)d_ws;                        // [0:4)
    unsigned* wcnt = (unsigned*)((char*)d_ws + 4);           // [4:8)
    double*   wsum = (double*)((char*)d_ws + 8);             // [8:16)
    unsigned* hist = (unsigned*)((char*)d_ws + 16);          // 2048 uints
    unsigned* offs = (unsigned*)((char*)d_ws + 8208);        // 2048 uints
    int*      perm = (int*)((char*)d_ws + 16400);            // 2048 ints

    hipMemsetAsync(d_ws, 0, 16, stream);
    hipMemsetAsync(hist, 0, VV * sizeof(unsigned), stream);

    max_kernel<<<1024, 256, 0, stream>>>((const float4*)mapd, wmax, (VV * VV) / 4);
    hist_kernel<<<NL / 256, 256, 0, stream>>>(ids, hist);
    scan_kernel<<<1, 256, 0, stream>>>(hist, offs);
    scatter_kernel<<<NL / 256, 256, 0, stream>>>(ids, offs, perm);

    dim3 grid(NL / BT, NL / BT);
    loss_kernel<<<grid, 256, 0, stream>>>(ids, emb, tree, mapd, perm, wmax, wsum, wcnt);

    finalize_kernel<<<1, 64, 0, stream>>>(wsum, wcnt, out);
}